// Round 13
// baseline (593.304 us; speedup 1.0000x reference)
//
#include <hip/hip_runtime.h>
#include <hip/hip_bf16.h>

// Problem constants
#define N_ATOMS 262144
#define B_SZ    64
#define H_DIM   256
#define R_DIM   512

#define TILE_ROWS 32
#define TPB       16                        // tiles per block
#define NBLOCKS   (N_ATOMS / (TILE_ROWS * TPB))   // 512

typedef __attribute__((ext_vector_type(8))) short bf16x8;
typedef __attribute__((ext_vector_type(4))) float f32x4;

static __device__ __forceinline__ short f2bf(float f) {
  unsigned u = __builtin_bit_cast(unsigned, f);
  u = (u + 0x7FFFu + ((u >> 16) & 1u)) >> 16;   // RNE
  return (short)u;
}

// v_cvt_pk_bf16_f32 (no builtin on gfx950 — inline asm, m240)
static __device__ __forceinline__ unsigned cvtpk(float lo, float hi) {
  unsigned r;
  asm("v_cvt_pk_bf16_f32 %0, %1, %2" : "=v"(r) : "v"(lo), "v"(hi));
  return r;
}

static __device__ __forceinline__ bf16x8 pack8(f32x4 a0, f32x4 a1) {
  unsigned u0 = cvtpk(a0[0], a0[1]);
  unsigned u1 = cvtpk(a0[2], a0[3]);
  unsigned u2 = cvtpk(a1[0], a1[1]);
  unsigned u3 = cvtpk(a1[2], a1[3]);
  bf16x8 v;
  v[0] = (short)(u0 & 0xFFFF); v[1] = (short)(u0 >> 16);
  v[2] = (short)(u1 & 0xFFFF); v[3] = (short)(u1 >> 16);
  v[4] = (short)(u2 & 0xFFFF); v[5] = (short)(u2 >> 16);
  v[6] = (short)(u3 & 0xFFFF); v[7] = (short)(u3 >> 16);
  return v;
}

// async global->LDS DMA, 16B/lane; LDS dest = wave-uniform base + lane*16
static __device__ __forceinline__ void async_copy16(const float* g, short* lds) {
  __builtin_amdgcn_global_load_lds(
      (const __attribute__((address_space(1))) unsigned int*)g,
      (__attribute__((address_space(3))) unsigned int*)lds,
      16, 0, 0);
}

// ---------------------------------------------------------------------------
// ABLATION PROBES: 5 passes x 268 MB h, DMA-only (no LDS reads, no stores).
// Identical instruction counts; ONLY the per-lane global address differs.
// probe_lin: one instr = one full 1 KB row (8 complete 128B lines).
// probe_str: r10's fragment pattern (16 rows x 64B per instr).
// ---------------------------------------------------------------------------
__global__ __launch_bounds__(512) void probe_lin(const float* __restrict__ h) {
  __shared__ short buf[8 * 512];
  int lane = threadIdx.x & 63, w = threadIdx.x >> 6;
  short* dst = &buf[w * 512];
  const float* hb = h + ((long)blockIdx.x * 512 + (long)w * 64) * H_DIM + (lane << 2);
  for (int p = 0; p < 5; ++p) {
    for (int i = 0; i < 64; i += 4) {
      async_copy16(hb + (long)(i + 0) * H_DIM, dst);
      async_copy16(hb + (long)(i + 1) * H_DIM, dst);
      async_copy16(hb + (long)(i + 2) * H_DIM, dst);
      async_copy16(hb + (long)(i + 3) * H_DIM, dst);
      asm volatile("s_waitcnt vmcnt(12)" ::: "memory");
    }
  }
  asm volatile("s_waitcnt vmcnt(0)" ::: "memory");
}

__global__ __launch_bounds__(512) void probe_str(const float* __restrict__ h) {
  __shared__ short buf[8 * 512];
  int lane = threadIdx.x & 63, w = threadIdx.x >> 6;
  int arow = lane & 15, kg = lane >> 4;
  short* dst = &buf[w * 512];
  long base = (long)blockIdx.x * 512;
  int row_[4], col_[4];
#pragma unroll
  for (int i = 0; i < 4; ++i) {
    int S   = 4 * w + i;
    row_[i] = ((S >> 4) << 4) + arow;
    col_[i] = (((S >> 1) & 7) << 5) + (kg << 3) + ((S & 1) << 2);
  }
  for (int p = 0; p < 5; ++p) {
    for (int tt = 0; tt < 16; ++tt) {
      long g0 = base + (long)tt * 32;
#pragma unroll
      for (int i = 0; i < 4; ++i)
        async_copy16(h + (g0 + row_[i]) * H_DIM + col_[i], dst);
      asm volatile("s_waitcnt vmcnt(12)" ::: "memory");
    }
  }
  asm volatile("s_waitcnt vmcnt(0)" ::: "memory");
}

// ---------------------------------------------------------------------------
// Prep kernel (unchanged):
//   blocks [0,64):  pooled[b][o] = bl[o] + retj . Wl[o,256:512]
//   blocks [64,80): Bbf fragment-order bf16 conversion of Wl[:, :256]
// ---------------------------------------------------------------------------
__global__ __launch_bounds__(1024) void prep_kernel(
    const float* __restrict__ rf, const float* __restrict__ Wp,
    const float* __restrict__ bp, const float* __restrict__ Wl,
    const float* __restrict__ bl, float* __restrict__ pooled,
    short* __restrict__ Bbf) {
  int t = threadIdx.x;
  if (blockIdx.x >= B_SZ) {
    int base = (blockIdx.x - B_SZ) * 4096 + t * 4;
#pragma unroll
    for (int q = 0; q < 4; ++q) {
      int idx  = base + q;
      int j    = idx & 7;
      int lane = (idx >> 3) & 63;
      int ks   = (idx >> 9) & 7;
      int ct   = idx >> 12;
      int o    = ct * 16 + (lane & 15);
      int k    = ks * 32 + ((lane >> 4) << 3) + j;
      Bbf[idx] = f2bf(Wl[o * (2 * H_DIM) + k]);
    }
    return;
  }

  __shared__ float meanr[R_DIM];
  __shared__ float retj[H_DIM];
  int b    = blockIdx.x;
  int lane = t & 63;
  int w    = t >> 6;            // 16 waves

  if (t < R_DIM) {
    float s = 0.f;
    const float* p = rf + (long)b * 16 * R_DIM + t;
#pragma unroll
    for (int k = 0; k < 16; ++k) s += p[k * R_DIM];
    meanr[t] = s * (1.f / 16.f);
  }
  __syncthreads();

  {
    f32x4 m0 = *(const f32x4*)&meanr[lane * 8];
    f32x4 m1 = *(const f32x4*)&meanr[lane * 8 + 4];
#pragma unroll
    for (int jj = 0; jj < 16; ++jj) {
      int j = w * 16 + jj;
      const f32x4* wp = (const f32x4*)(Wp + (long)j * R_DIM + lane * 8);
      f32x4 w0 = wp[0], w1 = wp[1];
      float s = m0[0]*w0[0] + m0[1]*w0[1] + m0[2]*w0[2] + m0[3]*w0[3]
              + m1[0]*w1[0] + m1[1]*w1[1] + m1[2]*w1[2] + m1[3]*w1[3];
#pragma unroll
      for (int d = 1; d < 64; d <<= 1) s += __shfl_xor(s, d);
      if (lane == 0) retj[j] = s + bp[j];
    }
  }
  __syncthreads();

  {
    f32x4 r0 = *(const f32x4*)&retj[lane * 4];
#pragma unroll
    for (int oo = 0; oo < 16; ++oo) {
      int o = w * 16 + oo;
      f32x4 wv = *(const f32x4*)(Wl + (long)o * (2 * H_DIM) + H_DIM + lane * 4);
      float s = r0[0]*wv[0] + r0[1]*wv[1] + r0[2]*wv[2] + r0[3]*wv[3];
#pragma unroll
      for (int d = 1; d < 64; d <<= 1) s += __shfl_xor(s, d);
      if (lane == 0) pooled[b * H_DIM + o] = s + bl[o];
    }
  }
}

// ---------------------------------------------------------------------------
// GEMM (r10 structure; NEW staging): out[n][o] = h[n]·Wl[o] + pooled[batch[n]][o]
// LDS is ROW-MAJOR with XOR swizzle: unit16 (r,u) holds h[g0+r][chunk u^(r&7)].
//  - DMA: wave w stages rows 4w+i; src = row base + ((lane^(r&7))<<4) bytes —
//    permutes 16B units WITHIN 128B lines only => one instr = one full 1 KB
//    row = 8 complete cache lines (the linear pattern). Dest = r*1024 linear.
//  - ds_read: addr = R*1024 + (((ks*8+kg*2+hk) ^ (R&7))<<4); per 16-lane
//    phase residues (c16^arow&7)&7 hit 8 banksets x2 lanes => 2-way (free).
// Content identical to r10 => same MFMA math, same absmax.
// ---------------------------------------------------------------------------
__global__ __launch_bounds__(512, 4) void gemm_kernel(
    const float* __restrict__ h, const short* __restrict__ Bbf,
    const float* __restrict__ pooled, const int* __restrict__ batch,
    float* __restrict__ out) {
  __shared__ short As[2][32 * 512];        // 2 x 32 KiB (f32 rows, swizzled)
  int t    = threadIdx.x;
  int lane = t & 63;
  int w    = t >> 6;                        // 0..7
  const int arow = lane & 15;
  const int kg   = lane >> 4;               // 0..3

  // --- B strips for col-tiles 2w, 2w+1 (loaded once, 64 VGPR) ---
  bf16x8 bfrag0[8], bfrag1[8];
#pragma unroll
  for (int ks = 0; ks < 8; ++ks) {
    bfrag0[ks] = *(const bf16x8*)(Bbf + ((((2 * w)     * 8 + ks) * 64 + lane) << 3));
    bfrag1[ks] = *(const bf16x8*)(Bbf + ((((2 * w + 1) * 8 + ks) * 64 + lane) << 3));
  }

  // staging geometry: wave w stages rows 4w..4w+3; per-lane swizzled source
  int r_[4], lx_[4];
#pragma unroll
  for (int i = 0; i < 4; ++i) {
    int r  = 4 * w + i;
    r_[i]  = r;
    lx_[i] = (lane ^ (r & 7)) << 2;   // float offset within the row
  }

  long base_row = (long)blockIdx.x * (TILE_ROWS * TPB);

  // --- prologue: stage tile 0 into buf 0 ---
#pragma unroll
  for (int i = 0; i < 4; ++i)
    async_copy16(h + (base_row + r_[i]) * H_DIM + lx_[i],
                 &As[0][r_[i] * 512]);
  __syncthreads();

  int o0 = ((2 * w) << 4) + (kg << 2);
  int o1 = o0 + 16;
  const int msk = arow & 7;
  const int cb  = kg << 1;                  // c16 base bits from kg

  for (int tt = 0; tt < TPB; ++tt) {
    int  buf = tt & 1;
    long g0  = base_row + (long)tt * TILE_ROWS;
    bool more = (tt + 1 < TPB);

    // --- (1) epilogue VMEM loads BEFORE DMA issue (r10's fix) ---
    long row0 = g0 + arow;
    long row1 = g0 + 16 + arow;
    int  b0 = batch[row0];
    int  b1 = batch[row1];
    const float* pb0 = pooled + b0 * H_DIM;
    const float* pb1 = pooled + b1 * H_DIM;
    f32x4 pv00 = *(const f32x4*)(pb0 + o0);
    f32x4 pv01 = *(const f32x4*)(pb0 + o1);
    f32x4 pv10 = *(const f32x4*)(pb1 + o0);
    f32x4 pv11 = *(const f32x4*)(pb1 + o1);
    __builtin_amdgcn_sched_barrier(0);

    // --- (2) stage next tile (linear rows, swizzled lanes) ---
    if (more) {
      long gn = g0 + TILE_ROWS;
#pragma unroll
      for (int i = 0; i < 4; ++i)
        async_copy16(h + (gn + r_[i]) * H_DIM + lx_[i],
                     &As[buf ^ 1][r_[i] * 512]);
    }

    // --- (3) compute 2 row-tiles x 2 col-tiles ---
#pragma unroll
    for (int rt = 0; rt < 2; ++rt) {
      const char* rowb = (const char*)&As[buf][(rt * 16 + arow) * 512];
      f32x4 acc0 = {0.f, 0.f, 0.f, 0.f};
      f32x4 acc1 = {0.f, 0.f, 0.f, 0.f};
#pragma unroll
      for (int ks = 0; ks < 8; ++ks) {
        int c0 = ks * 8 + cb;
        f32x4 v0 = *(const f32x4*)(rowb + ((c0 ^ msk) << 4));
        f32x4 v1 = *(const f32x4*)(rowb + (((c0 + 1) ^ msk) << 4));
        bf16x8 af = pack8(v0, v1);
        acc0 = __builtin_amdgcn_mfma_f32_16x16x32_bf16(bfrag0[ks], af, acc0, 0, 0, 0);
        acc1 = __builtin_amdgcn_mfma_f32_16x16x32_bf16(bfrag1[ks], af, acc1, 0, 0, 0);
      }
      long row = (rt == 0) ? row0 : row1;
      f32x4 r0v = acc0 + ((rt == 0) ? pv00 : pv10);
      f32x4 r1v = acc1 + ((rt == 0) ? pv01 : pv11);
      float* orow = out + row * H_DIM;
      *(f32x4*)(orow + o0) = r0v;
      *(f32x4*)(orow + o1) = r1v;
    }

    __syncthreads();
  }
}

// ---------------------------------------------------------------------------
extern "C" void kernel_launch(void* const* d_in, const int* in_sizes, int n_in,
                              void* d_out, int out_size, void* d_ws, size_t ws_size,
                              hipStream_t stream) {
  const float* h   = (const float*)d_in[0];
  const float* rf  = (const float*)d_in[1];
  const int*   bat = (const int*)d_in[2];
  const float* Wp  = (const float*)d_in[3];
  const float* bp  = (const float*)d_in[4];
  const float* Wl  = (const float*)d_in[5];
  const float* bl  = (const float*)d_in[6];
  float* out = (float*)d_out;

  float* pooled = (float*)d_ws;                          // 64 KiB
  short* Bbf    = (short*)((char*)d_ws + 64 * 1024);     // 128 KiB

  // Ablation probes (diagnostic this round; deleted next round)
  probe_lin<<<NBLOCKS, 512, 0, stream>>>(h);
  probe_str<<<NBLOCKS, 512, 0, stream>>>(h);

  prep_kernel<<<B_SZ + 16, 1024, 0, stream>>>(rf, Wp, bp, Wl, bl, pooled, Bbf);
  gemm_kernel<<<NBLOCKS, 512, 0, stream>>>(h, Bbf, pooled, bat, out);
}

// Round 14
// 305.167 us; speedup vs baseline: 1.9442x; 1.9442x over previous
//
#include <hip/hip_runtime.h>
#include <hip/hip_bf16.h>

// Problem constants
#define N_ATOMS 262144
#define B_SZ    64
#define H_DIM   256
#define R_DIM   512

#define TILE_ROWS 32
#define TPB       16                        // tiles per block
#define NBLOCKS   (N_ATOMS / (TILE_ROWS * TPB))   // 512

typedef __attribute__((ext_vector_type(8))) short bf16x8;
typedef __attribute__((ext_vector_type(4))) float f32x4;

static __device__ __forceinline__ short f2bf(float f) {
  unsigned u = __builtin_bit_cast(unsigned, f);
  u = (u + 0x7FFFu + ((u >> 16) & 1u)) >> 16;   // RNE
  return (short)u;
}

// v_cvt_pk_bf16_f32 (no builtin on gfx950 — inline asm, m240)
static __device__ __forceinline__ unsigned cvtpk(float lo, float hi) {
  unsigned r;
  asm("v_cvt_pk_bf16_f32 %0, %1, %2" : "=v"(r) : "v"(lo), "v"(hi));
  return r;
}

static __device__ __forceinline__ bf16x8 pack8(f32x4 a0, f32x4 a1) {
  unsigned u0 = cvtpk(a0[0], a0[1]);
  unsigned u1 = cvtpk(a0[2], a0[3]);
  unsigned u2 = cvtpk(a1[0], a1[1]);
  unsigned u3 = cvtpk(a1[2], a1[3]);
  bf16x8 v;
  v[0] = (short)(u0 & 0xFFFF); v[1] = (short)(u0 >> 16);
  v[2] = (short)(u1 & 0xFFFF); v[3] = (short)(u1 >> 16);
  v[4] = (short)(u2 & 0xFFFF); v[5] = (short)(u2 >> 16);
  v[6] = (short)(u3 & 0xFFFF); v[7] = (short)(u3 >> 16);
  return v;
}

// async global->LDS DMA, 16B/lane; LDS dest = wave-uniform base + lane*16
static __device__ __forceinline__ void async_copy16(const float* g, short* lds) {
  __builtin_amdgcn_global_load_lds(
      (const __attribute__((address_space(1))) unsigned int*)g,
      (__attribute__((address_space(3))) unsigned int*)lds,
      16, 0, 0);
}

// ---------------------------------------------------------------------------
// MIXED-STREAM PROBE: exact gemm traffic shape, zero compute.
// 2 passes x (DMA-read 268 MB of h + full-line dwordx4 stores of 268 MB to
// out). No barriers, no LDS reads; vmcnt-paced like probe_lin (which hit the
// 6.4 TB/s read ceiling). out is fully overwritten by gemm afterwards.
// Measures the HBM mixed read+write ceiling for the gemm's access shape.
// ---------------------------------------------------------------------------
__global__ __launch_bounds__(512) void probe_rw(const float* __restrict__ h,
                                                float* __restrict__ out) {
  __shared__ short buf[8 * 512];
  int lane = threadIdx.x & 63, w = threadIdx.x >> 6;
  short* dst = &buf[w * 512];
  long r0 = (long)blockIdx.x * 512 + (long)w * 64;
  const float* hb = h + r0 * H_DIM + (lane << 2);
  float*       ob = out + r0 * H_DIM + (lane << 2);
  f32x4 val = {1.f, 2.f, 3.f, 4.f};
  for (int p = 0; p < 2; ++p) {
    for (int i = 0; i < 64; i += 4) {
#pragma unroll
      for (int j = 0; j < 4; ++j) {
        async_copy16(hb + (long)(i + j) * H_DIM, dst);
        *(f32x4*)(ob + (long)(i + j) * H_DIM) = val;
      }
      asm volatile("s_waitcnt vmcnt(24)" ::: "memory");
    }
  }
  asm volatile("s_waitcnt vmcnt(0)" ::: "memory");
}

// ---------------------------------------------------------------------------
// Prep kernel (unchanged):
//   blocks [0,64):  pooled[b][o] = bl[o] + retj . Wl[o,256:512]
//   blocks [64,80): Bbf fragment-order bf16 conversion of Wl[:, :256]
// ---------------------------------------------------------------------------
__global__ __launch_bounds__(1024) void prep_kernel(
    const float* __restrict__ rf, const float* __restrict__ Wp,
    const float* __restrict__ bp, const float* __restrict__ Wl,
    const float* __restrict__ bl, float* __restrict__ pooled,
    short* __restrict__ Bbf) {
  int t = threadIdx.x;
  if (blockIdx.x >= B_SZ) {
    int base = (blockIdx.x - B_SZ) * 4096 + t * 4;
#pragma unroll
    for (int q = 0; q < 4; ++q) {
      int idx  = base + q;
      int j    = idx & 7;
      int lane = (idx >> 3) & 63;
      int ks   = (idx >> 9) & 7;
      int ct   = idx >> 12;
      int o    = ct * 16 + (lane & 15);
      int k    = ks * 32 + ((lane >> 4) << 3) + j;
      Bbf[idx] = f2bf(Wl[o * (2 * H_DIM) + k]);
    }
    return;
  }

  __shared__ float meanr[R_DIM];
  __shared__ float retj[H_DIM];
  int b    = blockIdx.x;
  int lane = t & 63;
  int w    = t >> 6;            // 16 waves

  if (t < R_DIM) {
    float s = 0.f;
    const float* p = rf + (long)b * 16 * R_DIM + t;
#pragma unroll
    for (int k = 0; k < 16; ++k) s += p[k * R_DIM];
    meanr[t] = s * (1.f / 16.f);
  }
  __syncthreads();

  {
    f32x4 m0 = *(const f32x4*)&meanr[lane * 8];
    f32x4 m1 = *(const f32x4*)&meanr[lane * 8 + 4];
#pragma unroll
    for (int jj = 0; jj < 16; ++jj) {
      int j = w * 16 + jj;
      const f32x4* wp = (const f32x4*)(Wp + (long)j * R_DIM + lane * 8);
      f32x4 w0 = wp[0], w1 = wp[1];
      float s = m0[0]*w0[0] + m0[1]*w0[1] + m0[2]*w0[2] + m0[3]*w0[3]
              + m1[0]*w1[0] + m1[1]*w1[1] + m1[2]*w1[2] + m1[3]*w1[3];
#pragma unroll
      for (int d = 1; d < 64; d <<= 1) s += __shfl_xor(s, d);
      if (lane == 0) retj[j] = s + bp[j];
    }
  }
  __syncthreads();

  {
    f32x4 r0 = *(const f32x4*)&retj[lane * 4];
#pragma unroll
    for (int oo = 0; oo < 16; ++oo) {
      int o = w * 16 + oo;
      f32x4 wv = *(const f32x4*)(Wl + (long)o * (2 * H_DIM) + H_DIM + lane * 4);
      float s = r0[0]*wv[0] + r0[1]*wv[1] + r0[2]*wv[2] + r0[3]*wv[3];
#pragma unroll
      for (int d = 1; d < 64; d <<= 1) s += __shfl_xor(s, d);
      if (lane == 0) pooled[b * H_DIM + o] = s + bl[o];
    }
  }
}

// ---------------------------------------------------------------------------
// GEMM: exact r10 structure (best known: 144 µs total).
// out[n][o] = sum_k h[n][k]*Wl[o][k] + pooled[batch[n]][o]
// 512 persistent blocks x 512 threads (8 waves), 16 tiles of 32 rows,
// double-buffered LDS via global_load_lds; epilogue loads hoisted above the
// DMA issue (pinned by sched_barrier) so their use-waits never drain the
// in-flight DMAs; plain full-line stores; __syncthreads per tile.
// ---------------------------------------------------------------------------
__global__ __launch_bounds__(512, 4) void gemm_kernel(
    const float* __restrict__ h, const short* __restrict__ Bbf,
    const float* __restrict__ pooled, const int* __restrict__ batch,
    float* __restrict__ out) {
  __shared__ short As[2][32 * 512];        // 2 x 32 KiB (raw f32 stripes)
  int t    = threadIdx.x;
  int lane = t & 63;
  int w    = t >> 6;                        // 0..7
  const int arow = lane & 15;
  const int kg   = lane >> 4;               // 0..3

  // --- B strips for col-tiles 2w, 2w+1 (loaded once, 64 VGPR) ---
  bf16x8 bfrag0[8], bfrag1[8];
#pragma unroll
  for (int ks = 0; ks < 8; ++ks) {
    bfrag0[ks] = *(const bf16x8*)(Bbf + ((((2 * w)     * 8 + ks) * 64 + lane) << 3));
    bfrag1[ks] = *(const bf16x8*)(Bbf + ((((2 * w + 1) * 8 + ks) * 64 + lane) << 3));
  }

  // stage geometry: wave w DMAs stripes 4w..4w+3 of a tile
  int S_[4], row_[4], col_[4];
#pragma unroll
  for (int i = 0; i < 4; ++i) {
    int S   = 4 * w + i;
    S_[i]   = S;
    row_[i] = ((S >> 4) << 4) + arow;
    col_[i] = (((S >> 1) & 7) << 5) + (kg << 3) + ((S & 1) << 2);
  }

  long base_row = (long)blockIdx.x * (TILE_ROWS * TPB);

  // --- prologue: stage tile 0 into buf 0 ---
#pragma unroll
  for (int i = 0; i < 4; ++i)
    async_copy16(h + (base_row + row_[i]) * H_DIM + col_[i],
                 &As[0][S_[i] * 512]);
  __syncthreads();

  int o0 = ((2 * w) << 4) + (kg << 2);
  int o1 = o0 + 16;

  for (int tt = 0; tt < TPB; ++tt) {
    int  buf = tt & 1;
    long g0  = base_row + (long)tt * TILE_ROWS;

    // --- (1) epilogue VMEM loads for CURRENT tile, BEFORE any DMA issue ---
    long row0 = g0 + arow;
    long row1 = g0 + 16 + arow;
    int  b0 = batch[row0];
    int  b1 = batch[row1];
    const float* pb0 = pooled + b0 * H_DIM;
    const float* pb1 = pooled + b1 * H_DIM;
    f32x4 pv00 = *(const f32x4*)(pb0 + o0);
    f32x4 pv01 = *(const f32x4*)(pb0 + o1);
    f32x4 pv10 = *(const f32x4*)(pb1 + o0);
    f32x4 pv11 = *(const f32x4*)(pb1 + o1);
    __builtin_amdgcn_sched_barrier(0);   // pin: loads above, DMAs below

    // --- (2) stage next tile into other buffer (flies across compute) ---
    if (tt + 1 < TPB) {
      long gn = g0 + TILE_ROWS;
#pragma unroll
      for (int i = 0; i < 4; ++i)
        async_copy16(h + (gn + row_[i]) * H_DIM + col_[i],
                     &As[buf ^ 1][S_[i] * 512]);
    }

    // --- (3) compute 2 row-tiles x 2 col-tiles from buf (LDS + regs only) ---
#pragma unroll
    for (int rt = 0; rt < 2; ++rt) {
      f32x4 acc0 = {0.f, 0.f, 0.f, 0.f};
      f32x4 acc1 = {0.f, 0.f, 0.f, 0.f};
#pragma unroll
      for (int ks = 0; ks < 8; ++ks) {
        int S0 = rt * 16 + ks * 2;
        f32x4 v0 = *(const f32x4*)&As[buf][(S0 * 512) + lane * 8];
        f32x4 v1 = *(const f32x4*)&As[buf][((S0 + 1) * 512) + lane * 8];
        bf16x8 af = pack8(v0, v1);
        acc0 = __builtin_amdgcn_mfma_f32_16x16x32_bf16(bfrag0[ks], af, acc0, 0, 0, 0);
        acc1 = __builtin_amdgcn_mfma_f32_16x16x32_bf16(bfrag1[ks], af, acc1, 0, 0, 0);
      }
      long row = (rt == 0) ? row0 : row1;
      f32x4 r0v = acc0 + ((rt == 0) ? pv00 : pv10);
      f32x4 r1v = acc1 + ((rt == 0) ? pv01 : pv11);
      float* orow = out + row * H_DIM;
      *(f32x4*)(orow + o0) = r0v;
      *(f32x4*)(orow + o1) = r1v;
    }

    __syncthreads();
  }
}

// ---------------------------------------------------------------------------
extern "C" void kernel_launch(void* const* d_in, const int* in_sizes, int n_in,
                              void* d_out, int out_size, void* d_ws, size_t ws_size,
                              hipStream_t stream) {
  const float* h   = (const float*)d_in[0];
  const float* rf  = (const float*)d_in[1];
  const int*   bat = (const int*)d_in[2];
  const float* Wp  = (const float*)d_in[3];
  const float* bp  = (const float*)d_in[4];
  const float* Wl  = (const float*)d_in[5];
  const float* bl  = (const float*)d_in[6];
  float* out = (float*)d_out;

  float* pooled = (float*)d_ws;                          // 64 KiB
  short* Bbf    = (short*)((char*)d_ws + 64 * 1024);     // 128 KiB

  // Mixed-stream ablation probe (diagnostic; out is overwritten by gemm)
  probe_rw<<<NBLOCKS, 512, 0, stream>>>(h, out);

  prep_kernel<<<B_SZ + 16, 1024, 0, stream>>>(rf, Wp, bp, Wl, bl, pooled, Bbf);
  gemm_kernel<<<NBLOCKS, 512, 0, stream>>>(h, Bbf, pooled, bat, out);
}

// Round 15
// 144.784 us; speedup vs baseline: 4.0979x; 2.1077x over previous
//
#include <hip/hip_runtime.h>
#include <hip/hip_bf16.h>

// Problem constants
#define N_ATOMS 262144
#define B_SZ    64
#define H_DIM   256
#define R_DIM   512

#define TILE_ROWS 16
#define TPB       32                               // tiles per block
#define NBLOCKS   (N_ATOMS / (TILE_ROWS * TPB))    // 512
#define NBUF      4

typedef __attribute__((ext_vector_type(8))) short bf16x8;
typedef __attribute__((ext_vector_type(4))) float f32x4;

static __device__ __forceinline__ short f2bf(float f) {
  unsigned u = __builtin_bit_cast(unsigned, f);
  u = (u + 0x7FFFu + ((u >> 16) & 1u)) >> 16;   // RNE
  return (short)u;
}

// v_cvt_pk_bf16_f32 (no builtin on gfx950 — inline asm, m240)
static __device__ __forceinline__ unsigned cvtpk(float lo, float hi) {
  unsigned r;
  asm("v_cvt_pk_bf16_f32 %0, %1, %2" : "=v"(r) : "v"(lo), "v"(hi));
  return r;
}

static __device__ __forceinline__ bf16x8 pack8(f32x4 a0, f32x4 a1) {
  unsigned u0 = cvtpk(a0[0], a0[1]);
  unsigned u1 = cvtpk(a0[2], a0[3]);
  unsigned u2 = cvtpk(a1[0], a1[1]);
  unsigned u3 = cvtpk(a1[2], a1[3]);
  bf16x8 v;
  v[0] = (short)(u0 & 0xFFFF); v[1] = (short)(u0 >> 16);
  v[2] = (short)(u1 & 0xFFFF); v[3] = (short)(u1 >> 16);
  v[4] = (short)(u2 & 0xFFFF); v[5] = (short)(u2 >> 16);
  v[6] = (short)(u3 & 0xFFFF); v[7] = (short)(u3 >> 16);
  return v;
}

// async global->LDS DMA, 16B/lane; LDS dest = wave-uniform base + lane*16
static __device__ __forceinline__ void async_copy16(const float* g, short* lds) {
  __builtin_amdgcn_global_load_lds(
      (const __attribute__((address_space(1))) unsigned int*)g,
      (__attribute__((address_space(3))) unsigned int*)lds,
      16, 0, 0);
}

// ---------------------------------------------------------------------------
// Prep kernel (unchanged):
//   blocks [0,64):  pooled[b][o] = bl[o] + retj . Wl[o,256:512]
//   blocks [64,80): Bbf fragment-order bf16 conversion of Wl[:, :256]
// ---------------------------------------------------------------------------
__global__ __launch_bounds__(1024) void prep_kernel(
    const float* __restrict__ rf, const float* __restrict__ Wp,
    const float* __restrict__ bp, const float* __restrict__ Wl,
    const float* __restrict__ bl, float* __restrict__ pooled,
    short* __restrict__ Bbf) {
  int t = threadIdx.x;
  if (blockIdx.x >= B_SZ) {
    int base = (blockIdx.x - B_SZ) * 4096 + t * 4;
#pragma unroll
    for (int q = 0; q < 4; ++q) {
      int idx  = base + q;
      int j    = idx & 7;
      int lane = (idx >> 3) & 63;
      int ks   = (idx >> 9) & 7;
      int ct   = idx >> 12;
      int o    = ct * 16 + (lane & 15);
      int k    = ks * 32 + ((lane >> 4) << 3) + j;
      Bbf[idx] = f2bf(Wl[o * (2 * H_DIM) + k]);
    }
    return;
  }

  __shared__ float meanr[R_DIM];
  __shared__ float retj[H_DIM];
  int b    = blockIdx.x;
  int lane = t & 63;
  int w    = t >> 6;            // 16 waves

  if (t < R_DIM) {
    float s = 0.f;
    const float* p = rf + (long)b * 16 * R_DIM + t;
#pragma unroll
    for (int k = 0; k < 16; ++k) s += p[k * R_DIM];
    meanr[t] = s * (1.f / 16.f);
  }
  __syncthreads();

  {
    f32x4 m0 = *(const f32x4*)&meanr[lane * 8];
    f32x4 m1 = *(const f32x4*)&meanr[lane * 8 + 4];
#pragma unroll
    for (int jj = 0; jj < 16; ++jj) {
      int j = w * 16 + jj;
      const f32x4* wp = (const f32x4*)(Wp + (long)j * R_DIM + lane * 8);
      f32x4 w0 = wp[0], w1 = wp[1];
      float s = m0[0]*w0[0] + m0[1]*w0[1] + m0[2]*w0[2] + m0[3]*w0[3]
              + m1[0]*w1[0] + m1[1]*w1[1] + m1[2]*w1[2] + m1[3]*w1[3];
#pragma unroll
      for (int d = 1; d < 64; d <<= 1) s += __shfl_xor(s, d);
      if (lane == 0) retj[j] = s + bp[j];
    }
  }
  __syncthreads();

  {
    f32x4 r0 = *(const f32x4*)&retj[lane * 4];
#pragma unroll
    for (int oo = 0; oo < 16; ++oo) {
      int o = w * 16 + oo;
      f32x4 wv = *(const f32x4*)(Wl + (long)o * (2 * H_DIM) + H_DIM + lane * 4);
      float s = r0[0]*wv[0] + r0[1]*wv[1] + r0[2]*wv[2] + r0[3]*wv[3];
#pragma unroll
      for (int d = 1; d < 64; d <<= 1) s += __shfl_xor(s, d);
      if (lane == 0) pooled[b * H_DIM + o] = s + bl[o];
    }
  }
}

// ---------------------------------------------------------------------------
// GEMM: out[n][o] = sum_k h[n][k]*Wl[o][k] + pooled[batch[n]][o]
// 512 blocks x 512 threads (8 waves); 32 tiles of 16 rows; 4 LDS A-buffers.
//
// DESIGN: per-iteration VMEM = exactly {2 DMA, 2 stores} — NOTHING else.
//  * batch is SORTED -> a block's 512 rows span 1-2 pooled rows. Prologue
//    stages boff[512] (short) + the pooled slice (span<=8 rows, 8 KB) into
//    LDS; per-iter pv reads are ds_reads (lgkmcnt) — the vmcnt queue never
//    carries a dependent load. (Uniform global fallback if span>8: correct,
//    slower, statistically never taken.)
//  * Tail iters issue dummy DMAs into scratch so op counts stay uniform.
//  * s_waitcnt vmcnt(10): with 4 ops/iter this retains DMA(t+1),(t+2),(t+3)
//    (6 KB/wave, 96 KB/CU reads in flight) and provably drains DMA(t)
//    (12 younger ops >= 10). r12's vmcnt(9) over-drained to 2 tiles.
//  * Raw s_barrier per tile (NOT __syncthreads = vmcnt(0) drain). One full
//    drain only in the prologue. Buffer safety: DMA(t+3)->buf (t+3)%4 issued
//    after the barrier that ends compute(t-1) on buf (t-1)%4 == (t+3)%4.
//
// LDS stripe S in [0,16): lane's 16B at S*1024+lane*16 =
// h[g0+(lane&15)][(S>>1)*32+(lane>>4)*8+(S&1)*4 ..+3]; wave w DMAs stripes
// {2w,2w+1}; ds_read_b128 lane-linear (0 conflicts, r4/r8/r12-verified).
// Wave w owns col-tiles {2w,2w+1}; B strips in registers (64 VGPR).
// SWAPPED MFMA: row=lane&15, cols=32w+(lane>>4)*4 (+16) -> the wave writes
// cols [32w,32w+32) of each row: full 128B segments per iteration.
// ---------------------------------------------------------------------------
__global__ __launch_bounds__(512, 4) void gemm_kernel(
    const float* __restrict__ h, const short* __restrict__ Bbf,
    const float* __restrict__ pooled, const int* __restrict__ batch,
    float* __restrict__ out) {
  __shared__ short As[NBUF][16 * 512];     // 64 KiB
  __shared__ float pooled_lds[8 * 256];    // 8 KiB
  __shared__ short boff_lds[512];          // 1 KiB
  __shared__ short scratch[512];           // 1 KiB (dummy DMA dest)
  int t    = threadIdx.x;
  int lane = t & 63;
  int w    = t >> 6;                        // 0..7
  const int arow = lane & 15;
  const int kg   = lane >> 4;               // 0..3

  // --- B strips for col-tiles 2w, 2w+1 (loaded once, 64 VGPR) ---
  bf16x8 bfrag0[8], bfrag1[8];
#pragma unroll
  for (int ks = 0; ks < 8; ++ks) {
    bfrag0[ks] = *(const bf16x8*)(Bbf + ((((2 * w)     * 8 + ks) * 64 + lane) << 3));
    bfrag1[ks] = *(const bf16x8*)(Bbf + ((((2 * w + 1) * 8 + ks) * 64 + lane) << 3));
  }

  long base_row = (long)blockIdx.x * (TILE_ROWS * TPB);   // 512 rows/block
  int o0 = (w << 5) + (kg << 2);                           // 32w + 4kg
  int o1 = o0 + 16;
  const long lsrc = (long)arow * H_DIM + (w << 5) + (kg << 3);

  // --- prologue ---
  int b_t     = batch[base_row + t];          // this thread's row's batch id
  int b_first = batch[base_row];              // sorted => block min
  int b_last  = batch[base_row + 511];        // sorted => block max
  int span    = b_last - b_first + 1;

#pragma unroll
  for (int tl = 0; tl < 3; ++tl) {            // DMA tiles 0..2
    const float* gp = h + (base_row + (long)tl * TILE_ROWS) * H_DIM + lsrc;
    async_copy16(gp,     &As[tl][(2 * w) * 512]);
    async_copy16(gp + 4, &As[tl][(2 * w + 1) * 512]);
  }

  boff_lds[t] = (short)(b_t - b_first);
  if (span <= 8) {                            // stage pooled slice (<=8 KB)
    int fi = t * 4;
    if (fi < span * H_DIM)
      *(f32x4*)&pooled_lds[fi] =
          *(const f32x4*)(pooled + (long)b_first * H_DIM + fi);
  }
  asm volatile("s_waitcnt vmcnt(0) lgkmcnt(0)" ::: "memory");  // once
  __builtin_amdgcn_s_barrier();
  __builtin_amdgcn_sched_barrier(0);

  const bool small_span = (span <= 8);

  for (int tt = 0; tt < TPB; ++tt) {
    long g0 = base_row + (long)tt * TILE_ROWS;

    // --- (1) DMA(t+3) (or dummy into scratch: uniform 2 ops every iter) ---
    {
      const float* gp;
      short *d0, *d1;
      if (tt + 3 < TPB) {
        gp = h + (g0 + 3 * TILE_ROWS) * H_DIM + lsrc;
        short* dbuf = &As[(tt + 3) & 3][0];
        d0 = dbuf + (2 * w) * 512;
        d1 = dbuf + (2 * w + 1) * 512;
      } else {
        gp = h + base_row * H_DIM + lsrc;     // any valid address
        d0 = scratch;
        d1 = scratch;
      }
      async_copy16(gp,     d0);
      async_copy16(gp + 4, d1);
    }
    __builtin_amdgcn_sched_barrier(0);
    // --- (2) pacing wait: drains DMA(t); retains DMA(t+1..t+3) + stores ---
    asm volatile("s_waitcnt vmcnt(10)" ::: "memory");
    __builtin_amdgcn_sched_barrier(0);

    // --- (3) compute tile t from As[tt&3] (LDS + regs only) ---
    const short* ab = &As[tt & 3][0];
    f32x4 acc0 = {0.f, 0.f, 0.f, 0.f};
    f32x4 acc1 = {0.f, 0.f, 0.f, 0.f};
#pragma unroll
    for (int ks = 0; ks < 8; ++ks) {
      f32x4 v0 = *(const f32x4*)(ab + ks * 1024 + lane * 8);
      f32x4 v1 = *(const f32x4*)(ab + ks * 1024 + 512 + lane * 8);
      bf16x8 af = pack8(v0, v1);
      acc0 = __builtin_amdgcn_mfma_f32_16x16x32_bf16(bfrag0[ks], af, acc0, 0, 0, 0);
      acc1 = __builtin_amdgcn_mfma_f32_16x16x32_bf16(bfrag1[ks], af, acc1, 0, 0, 0);
    }

    // --- (4) pv from LDS (lgkmcnt — never touches the vmcnt queue) ---
    int off = (int)boff_lds[tt * 16 + arow];
    f32x4 pv0, pv1;
    if (small_span) {
      pv0 = *(const f32x4*)&pooled_lds[(off << 8) + o0];
      pv1 = *(const f32x4*)&pooled_lds[(off << 8) + o1];
    } else {                                   // rare fallback: global pv
      const float* pb = pooled + (long)(b_first + off) * H_DIM;
      pv0 = *(const f32x4*)(pb + o0);
      pv1 = *(const f32x4*)(pb + o1);
    }

    float* orow = out + (g0 + arow) * H_DIM;
    *(f32x4*)(orow + o0) = acc0 + pv0;
    *(f32x4*)(orow + o1) = acc1 + pv1;

    // --- (5) raw barrier: cross-wave LDS handoff, NO vmcnt drain ---
    __builtin_amdgcn_s_barrier();
    __builtin_amdgcn_sched_barrier(0);
  }
}

// ---------------------------------------------------------------------------
extern "C" void kernel_launch(void* const* d_in, const int* in_sizes, int n_in,
                              void* d_out, int out_size, void* d_ws, size_t ws_size,
                              hipStream_t stream) {
  const float* h   = (const float*)d_in[0];
  const float* rf  = (const float*)d_in[1];
  const int*   bat = (const int*)d_in[2];
  const float* Wp  = (const float*)d_in[3];
  const float* bp  = (const float*)d_in[4];
  const float* Wl  = (const float*)d_in[5];
  const float* bl  = (const float*)d_in[6];
  float* out = (float*)d_out;

  float* pooled = (float*)d_ws;                          // 64 KiB
  short* Bbf    = (short*)((char*)d_ws + 64 * 1024);     // 128 KiB

  prep_kernel<<<B_SZ + 16, 1024, 0, stream>>>(rf, Wp, bp, Wl, bl, pooled, Bbf);
  gemm_kernel<<<NBLOCKS, 512, 0, stream>>>(h, Bbf, pooled, bat, out);
}